// Round 2
// baseline (1313.282 us; speedup 1.0000x reference)
//
#include <hip/hip_runtime.h>
#include <hip/hip_bf16.h>
#include <stdint.h>

// ---------------------------------------------------------------------------
// MixModel fused kernel (MI355X / gfx950)
//
// Strategy: keep all per-sample "messages" (9x9 chunks of 16 fp16) resident in
// VGPRs across all 6 layers. Transposed GEMM (M=out_features, N=samples) with
// v_mfma_f32_16x16x16_f16: the C/D fragment layout equals the B fragment
// layout, so layer-to-layer chunk transpose is free (register renaming with an
// alternating-parity in-place slot scheme). Weights are pre-converted to fp16
// MFMA-fragment order in d_ws by prologue kernels; the main kernel streams them
// global->LDS with global_load_lds (async), double-buffered per position step.
// ---------------------------------------------------------------------------

typedef __attribute__((ext_vector_type(4))) float    f32x4;
typedef __attribute__((ext_vector_type(4))) _Float16 f16x4;
typedef __attribute__((ext_vector_type(8))) _Float16 f16x8;
typedef unsigned long long u64;
typedef unsigned int u32;

#define STEP_BYTES 55296           // 9 Mtiles * 6 kc-pairs * 64 lanes * 16B
#define CMN_BYTES  45056           // padded (2816*16); real 81*64*8 = 41472
#define WS_LAYER   (54*STEP_BYTES) // 2,985,984
#define LDS_TOTAL  (2*STEP_BYTES + 4*9*1152)  // 110592 + 41472 = 152064

__device__ __forceinline__ unsigned short f2h(float f) {
  return __builtin_bit_cast(unsigned short, (_Float16)f);
}

__device__ __forceinline__ f32x4 mfma16(f16x4 a, f16x4 b, f32x4 c) {
#if __has_builtin(__builtin_amdgcn_mfma_f32_16x16x16f16)
  return __builtin_amdgcn_mfma_f32_16x16x16f16(a, b, c, 0, 0, 0);
#else
  asm("v_mfma_f32_16x16x16_f16 %0, %1, %2, %0" : "+v"(c) : "v"(a), "v"(b));
  return c;
#endif
}

// static feature value for (sample b, position o, padded k-index kidx in [0,48))
// layout: [0..8] mask row o | [9..17] board ch0 row o | [18..26] board ch1 row o
//         [27..35] g0 (ch0 row 9) | [36..44] g1 (ch1 row 9) | [45..47] zero pad
__device__ __forceinline__ float static_feat(const float* __restrict__ mask,
                                             const float* __restrict__ board,
                                             int b, int o, int kidx) {
  if (kidx < 9)  return mask [b*81  + o*9 + kidx];
  if (kidx < 18) return board[b*180 +       o*9 + (kidx - 9)];
  if (kidx < 27) return board[b*180 + 90 +  o*9 + (kidx - 18)];
  if (kidx < 36) return board[b*180 +       81 + (kidx - 27)];
  if (kidx < 45) return board[b*180 + 90 +  81 + (kidx - 36)];
  return 0.f;
}

// async stage one step's fragment block into LDS (wave-uniform dest + lane*16)
__device__ __forceinline__ void stage_step(int s, const unsigned char* __restrict__ ws,
                                           unsigned char* dstlds, int tid) {
  const unsigned char* src = (s < 54) ? (ws + (size_t)s * STEP_BYTES)
                                      : (ws + WS_LAYER + (size_t)(s - 54) * CMN_BYTES);
  const int n16 = (s < 54) ? (STEP_BYTES / 16) : (CMN_BYTES / 16);
  const int ubase = tid & ~63;
  for (int k = 0; k * 256 < n16; ++k) {
    const int idx = k * 256 + tid;
    if (idx < n16) {  // always a full wave active (n16 % 64 == 0)
      __builtin_amdgcn_global_load_lds(
          (const __attribute__((address_space(1))) void*)(src + (size_t)idx * 16),
          (__attribute__((address_space(3))) void*)(dstlds + (size_t)(k * 256 + ubase) * 16),
          16, 0, 0);
    }
  }
}

// B-fragment for k-chunk kc (0..11) of position O at parity P
template<int P, int O>
__device__ __forceinline__ f16x4 bfrag(int kc, const f16x4 (&st0)[2], const f16x4 (&st1)[2],
                                       const f16x4 (&stc)[2], const u64 (&msg)[9][9][2], int t) {
  if (kc == 0) return st0[t];
  if (kc == 1) return st1[t];
  if (kc == 2) return stc[t];
  const int i = kc - 3;
  return __builtin_bit_cast(f16x4, P ? msg[O][i][t] : msg[i][O][t]);
}

template<int P, int O>
__device__ __forceinline__ void do_position(
    int d, const unsigned char* __restrict__ wb, unsigned char* __restrict__ sc,
    u64 (&msg)[9][9][2], const f16x4 (&stc)[2],
    const float* __restrict__ mask, const float* __restrict__ board,
    const float* __restrict__ layer_b, int b0, int lane)
{
  const int s15 = lane & 15, hq = lane >> 4;

  // position-dependent static B-frags (k-chunks 0 and 1), both sample tiles
  f16x4 st0[2], st1[2];
#pragma unroll
  for (int t = 0; t < 2; ++t) {
    const int b = b0 + t * 16 + s15;
#pragma unroll
    for (int e = 0; e < 4; ++e) {
      st0[t][e] = (_Float16)static_feat(mask, board, b, O,      4 * hq + e);
      st1[t][e] = (_Float16)static_feat(mask, board, b, O, 16 + 4 * hq + e);
    }
  }

  const float* bias_base = layer_b + (size_t)(d * 9 + O) * 144;

  for (int jp = 0; jp < 9; jp += 3) {   // runtime M-tile loop (3 tiles/iter)
    f32x4 acc[3][2];
#pragma unroll
    for (int u = 0; u < 3; ++u) { acc[u][0] = 0.f; acc[u][1] = 0.f; }

#pragma unroll
    for (int u = 0; u < 3; ++u) {
      const unsigned char* arow = wb + (size_t)(jp + u) * 6144;
#pragma unroll
      for (int kp = 0; kp < 6; ++kp) {
        const f16x8 af = *(const f16x8*)(arow + (size_t)kp * 1024 + (size_t)lane * 16);
        const f16x4 alo = __builtin_shufflevector(af, af, 0, 1, 2, 3);
        const f16x4 ahi = __builtin_shufflevector(af, af, 4, 5, 6, 7);
#pragma unroll
        for (int t = 0; t < 2; ++t) {
          acc[u][t] = mfma16(alo, bfrag<P, O>(2 * kp,     st0, st1, stc, msg, t), acc[u][t]);
          acc[u][t] = mfma16(ahi, bfrag<P, O>(2 * kp + 1, st0, st1, stc, msg, t), acc[u][t]);
        }
      }
    }

    // bias + relu + fp16 pack, bounce via per-wave LDS scratch (runtime jp)
#pragma unroll
    for (int u = 0; u < 3; ++u) {
      const f32x4 bias = *(const f32x4*)(bias_base + (jp + u) * 16 + 4 * hq);
#pragma unroll
      for (int t = 0; t < 2; ++t) {
        const float v0 = fmaxf(acc[u][t][0] + bias[0], 0.f);
        const float v1 = fmaxf(acc[u][t][1] + bias[1], 0.f);
        const float v2 = fmaxf(acc[u][t][2] + bias[2], 0.f);
        const float v3 = fmaxf(acc[u][t][3] + bias[3], 0.f);
        const u32 p01 = (u32)f2h(v0) | ((u32)f2h(v1) << 16);
        const u32 p23 = (u32)f2h(v2) | ((u32)f2h(v3) << 16);
        unsigned char* p = sc + (size_t)(jp + u) * 1152 + (size_t)(t * 16 + s15) * 36 + 8 * hq;
        *(u32*)p = p01;
        *(u32*)(p + 4) = p23;
      }
    }
  }

  // read produced chunks back into msg slots (compile-time slot indices)
#pragma unroll
  for (int j = 0; j < 9; ++j) {
#pragma unroll
    for (int t = 0; t < 2; ++t) {
      const unsigned char* p = sc + (size_t)j * 1152 + (size_t)(t * 16 + s15) * 36 + 8 * hq;
      const u32 c0 = *(const u32*)p;
      const u32 c1 = *(const u32*)(p + 4);
      const u64 v = (u64)c0 | ((u64)c1 << 32);
      if (P) msg[O][j][t] = v; else msg[j][O][t] = v;
    }
  }
}

__global__ __launch_bounds__(256, 1) void mix_main(
    const float* __restrict__ mask, const float* __restrict__ board,
    const float* __restrict__ layer_b, const float* __restrict__ common_b,
    const float* __restrict__ wdl_w, const float* __restrict__ wdl_b,
    const unsigned char* __restrict__ ws, float* __restrict__ out, int Bt)
{
  extern __shared__ unsigned char lds[];
  const int tid = threadIdx.x;
  const int lane = tid & 63;
  const int wid = tid >> 6;
  const int s15 = lane & 15, hq = lane >> 4;
  const int b0 = blockIdx.x * 128 + wid * 32;
  unsigned char* sc = lds + 2 * STEP_BYTES + (size_t)wid * (9 * 1152);

  stage_step(0, ws, lds, tid);   // prologue stage of step 0 (buffer parity 0)

  u64 msg[9][9][2];
#pragma unroll
  for (int a = 0; a < 9; ++a)
#pragma unroll
    for (int b = 0; b < 9; ++b) { msg[a][b][0] = 0ull; msg[a][b][1] = 0ull; }

  // position-independent static B-frag (k-chunk 2: g0 tail + g1 + pad)
  f16x4 stc[2];
#pragma unroll
  for (int t = 0; t < 2; ++t) {
    const int b = b0 + t * 16 + s15;
#pragma unroll
    for (int e = 0; e < 4; ++e)
      stc[t][e] = (_Float16)static_feat(mask, board, b, 0, 32 + 4 * hq + e);
  }

#define DO_POS(P, O) { \
    asm volatile("s_waitcnt vmcnt(0)" ::: "memory"); \
    __syncthreads(); \
    const int step = d * 9 + (O); \
    if (step + 1 < 64) \
      stage_step(step + 1, ws, lds + (size_t)((step + 1) & 1) * STEP_BYTES, tid); \
    do_position<P, O>(d, lds + (size_t)(step & 1) * STEP_BYTES, sc, msg, stc, \
                      mask, board, layer_b, b0, lane); \
  }

  for (int dp = 0; dp < 3; ++dp) {
    { const int d = dp * 2;
      DO_POS(0,0) DO_POS(0,1) DO_POS(0,2) DO_POS(0,3) DO_POS(0,4)
      DO_POS(0,5) DO_POS(0,6) DO_POS(0,7) DO_POS(0,8) }
    { const int d = dp * 2 + 1;
      DO_POS(1,0) DO_POS(1,1) DO_POS(1,2) DO_POS(1,3) DO_POS(1,4)
      DO_POS(1,5) DO_POS(1,6) DO_POS(1,7) DO_POS(1,8) }
  }
#undef DO_POS

  // ---- common layer: (B x 1296) @ (1296 x 145), 10 M-tiles streamed ----
  float pw0[3] = {0.f, 0.f, 0.f}, pw1[3] = {0.f, 0.f, 0.f};
  for (int mt = 0; mt < 10; ++mt) {
    asm volatile("s_waitcnt vmcnt(0)" ::: "memory");
    __syncthreads();
    const int step = 54 + mt;
    if (step + 1 < 64)
      stage_step(step + 1, ws, lds + (size_t)((step + 1) & 1) * STEP_BYTES, tid);
    const unsigned char* cb = lds + (size_t)(step & 1) * STEP_BYTES;
    f32x4 a0 = 0.f, a1 = 0.f;
#pragma unroll
    for (int i = 0; i < 9; ++i) {
#pragma unroll
      for (int j = 0; j < 9; ++j) {
        const f16x4 af = *(const f16x4*)(cb + ((size_t)(i * 9 + j) * 64 + lane) * 8);
        a0 = mfma16(af, __builtin_bit_cast(f16x4, msg[i][j][0]), a0);
        a1 = mfma16(af, __builtin_bit_cast(f16x4, msg[i][j][1]), a1);
      }
    }
#pragma unroll
    for (int r = 0; r < 4; ++r) {
      const int c = mt * 16 + 4 * hq + r;
      const float bias = (c < 145) ? common_b[c] : 0.f;
      const float v0 = a0[r] + bias, v1 = a1[r] + bias;
      if (c < 81) {  // policy (no relu)
        out[(size_t)3 * Bt + (size_t)(b0 + s15) * 81 + c]      = v0;
        out[(size_t)3 * Bt + (size_t)(b0 + 16 + s15) * 81 + c] = v1;
      } else if (c < 145) {  // wdl hidden: relu then tiny matmul accumulation
        const float h0 = fmaxf(v0, 0.f), h1 = fmaxf(v1, 0.f);
        const int cc = c - 81;
#pragma unroll
        for (int w = 0; w < 3; ++w) {
          const float wv = wdl_w[cc * 3 + w];
          pw0[w] += h0 * wv;
          pw1[w] += h1 * wv;
        }
      }
    }
  }

  // reduce wdl partials across the 4 lane-quarters (same sample col)
#pragma unroll
  for (int w = 0; w < 3; ++w) {
    float v0 = pw0[w], v1 = pw1[w];
    v0 += __shfl_xor(v0, 16, 64); v0 += __shfl_xor(v0, 32, 64);
    v1 += __shfl_xor(v1, 16, 64); v1 += __shfl_xor(v1, 32, 64);
    if (hq == 0) {
      const float bb = wdl_b[w];
      out[(size_t)(b0 + s15) * 3 + w]      = v0 + bb;
      out[(size_t)(b0 + 16 + s15) * 3 + w] = v1 + bb;
    }
  }
}

// ---- prologue: layer weights -> fp16 A-fragment order -----------------------
// layout: [d*9+o][jtile 9][kcpair 6][lane 64] x 16B ; A row = lane&15 (=n_out
// within tile), k = 4*(lane>>4)+e ; k-index remap: static 0..44, pad 45..47,
// messages 48+16*i+mm  <->  original k = kidx-3
__global__ __launch_bounds__(256) void conv_layer_w(const float* __restrict__ lw,
                                                    unsigned char* __restrict__ dst) {
  const int gid = blockIdx.x * 256 + threadIdx.x;
  if (gid >= 54 * 9 * 6 * 64) return;
  const int lane = gid & 63;
  const int t = gid >> 6;
  const int kp = t % 6, t2 = t / 6;
  const int jp = t2 % 9, dop = t2 / 9;
  const int m = lane & 15, hq = lane >> 4;
  unsigned short v[8];
#pragma unroll
  for (int e = 0; e < 8; ++e) {
    const int kc = kp * 2 + (e >> 2);
    const int kidx = kc * 16 + 4 * hq + (e & 3);
    float f = 0.f;
    if (kidx < 45)       f = lw[((size_t)dop * 189 + kidx) * 144 + jp * 16 + m];
    else if (kidx >= 48) f = lw[((size_t)dop * 189 + (kidx - 3)) * 144 + jp * 16 + m];
    v[e] = f2h(f);
  }
  const u32 w0 = (u32)v[0] | ((u32)v[1] << 16);
  const u32 w1 = (u32)v[2] | ((u32)v[3] << 16);
  const u32 w2 = (u32)v[4] | ((u32)v[5] << 16);
  const u32 w3 = (u32)v[6] | ((u32)v[7] << 16);
  *(uint4*)(dst + (size_t)gid * 16) = make_uint4(w0, w1, w2, w3);
}

// ---- prologue: common weights -> fp16 A-fragment order ----------------------
// layout: [mtile 10][ci 81][lane 64] x 8B, c_out padded 145->160 with zeros
__global__ __launch_bounds__(256) void conv_common_w(const float* __restrict__ cw,
                                                     unsigned char* __restrict__ dst) {
  const int gid = blockIdx.x * 256 + threadIdx.x;
  if (gid >= 10 * 81 * 64) return;
  const int lane = gid & 63;
  const int t = gid >> 6;
  const int ci = t % 81, mt = t / 81;
  const int m = lane & 15, hq = lane >> 4;
  const int c = mt * 16 + m;
  unsigned short v[4];
#pragma unroll
  for (int e = 0; e < 4; ++e) {
    const int k = ci * 16 + 4 * hq + e;
    v[e] = f2h((c < 145) ? cw[(size_t)k * 145 + c] : 0.f);
  }
  const u32 w0 = (u32)v[0] | ((u32)v[1] << 16);
  const u32 w1 = (u32)v[2] | ((u32)v[3] << 16);
  *(uint2*)(dst + (size_t)WS_LAYER + (size_t)mt * CMN_BYTES + (size_t)ci * 512 + (size_t)lane * 8)
      = make_uint2(w0, w1);
}

extern "C" void kernel_launch(void* const* d_in, const int* in_sizes, int n_in,
                              void* d_out, int out_size, void* d_ws, size_t ws_size,
                              hipStream_t stream) {
  const float* mask     = (const float*)d_in[0];
  const float* board    = (const float*)d_in[1];
  const float* layer_w  = (const float*)d_in[2];
  const float* layer_b  = (const float*)d_in[3];
  const float* common_w = (const float*)d_in[4];
  const float* common_b = (const float*)d_in[5];
  const float* wdl_w    = (const float*)d_in[6];
  const float* wdl_b    = (const float*)d_in[7];
  float* out = (float*)d_out;
  unsigned char* ws = (unsigned char*)d_ws;
  const int Bt = in_sizes[0] / 81;   // 65536

  hipLaunchKernelGGL(conv_layer_w, dim3((54 * 9 * 6 * 64) / 256), dim3(256), 0, stream,
                     layer_w, ws);
  hipLaunchKernelGGL(conv_common_w, dim3((10 * 81 * 64 + 255) / 256), dim3(256), 0, stream,
                     common_w, ws);
  (void)hipFuncSetAttribute((const void*)mix_main,
                            hipFuncAttributeMaxDynamicSharedMemorySize, LDS_TOTAL);
  hipLaunchKernelGGL(mix_main, dim3(Bt / 128), dim3(256), LDS_TOTAL, stream,
                     mask, board, layer_b, common_b, wdl_w, wdl_b, ws, out, Bt);
}